// Round 2
// baseline (505.902 us; speedup 1.0000x reference)
//
#include <hip/hip_runtime.h>
#include <cstdint>
#include <cstddef>

// ====================================================================
// Attention block: out = softmax(mask? NEG : (QK^T*scale + bias)) V @ Wout^T
// B=8 L=1024 E=1024 H=16 A=64.
// Dtypes (harness contract, reference is fp32): float inputs -> const float*,
// bool mask -> const int*, output -> float*. Compute in bf16 MFMA.
// Workspace: Q,K,Vt,Vals bf16 = 67 MiB.
// ====================================================================

typedef __bf16 bf16;
typedef __attribute__((ext_vector_type(8))) __bf16 bf16x8;
typedef __attribute__((ext_vector_type(4))) float f32x4;

#define MFMA_BF16(a, b, c) __builtin_amdgcn_mfma_f32_16x16x32_bf16(a, b, c, 0, 0, 0)

static constexpr float SCALE_ = 0.125f;                     // 64^-0.5
static constexpr float NEGF  = -3.4028234663852886e38f;     // finfo(f32).min (finite!)

__device__ __forceinline__ void gload_lds16(const bf16* g, bf16* l) {
  __builtin_amdgcn_global_load_lds((const __attribute__((address_space(1))) void*)g,
                                   (__attribute__((address_space(3))) void*)l,
                                   16, 0, 0);
}

__device__ __forceinline__ bf16x8 cvt8(const float* p) {
  f32x4 a = *(const f32x4*)p;
  f32x4 b = *(const f32x4*)(p + 4);
  bf16x8 r = {(bf16)a[0], (bf16)a[1], (bf16)a[2], (bf16)a[3],
              (bf16)b[0], (bf16)b[1], (bf16)b[2], (bf16)b[3]};
  return r;
}

// --------------------------------------------------------------------
// Kernel 1: QKV projection.  C[8192,3072] = X[8192,1024] @ W[3072,1024]^T
// f32 inputs staged to LDS as bf16. Epilogue scatters into Q[B,H,L,A],
// K[B,H,L,A], Vt[B,H,A,L] (bf16). col n: h=n/192, r=n%192 (Q/K/V split).
// --------------------------------------------------------------------
__global__ __launch_bounds__(256) void k_qkv(const float* __restrict__ X,
                                             const float* __restrict__ W,
                                             bf16* __restrict__ Q,
                                             bf16* __restrict__ Kc,
                                             bf16* __restrict__ Vt) {
  constexpr int K = 1024;
  __shared__ __align__(16) bf16 As[128 * 64];
  __shared__ __align__(16) bf16 Bs[128 * 64];
  const int t = threadIdx.x;
  const int lane = t & 63, w = t >> 6;
  const int wr = w >> 1, wc = w & 1;
  const int li = lane & 15, g = lane >> 4;
  const int m0 = (blockIdx.x & 63) * 128;   // 64 m-tiles
  const int n0 = (blockIdx.x >> 6) * 128;   // 24 n-tiles

  f32x4 acc[4][4] = {};

  for (int kt = 0; kt < K; kt += 64) {
#pragma unroll
    for (int it = 0; it < 4; ++it) {
      int c = it * 256 + t;               // 0..1023, 8 bf16 elems each
      int row = c >> 3, col = (c & 7) << 3;
      *(bf16x8*)(As + c * 8) = cvt8(X + (size_t)(m0 + row) * K + kt + col);
      *(bf16x8*)(Bs + c * 8) = cvt8(W + (size_t)(n0 + row) * K + kt + col);
    }
    __syncthreads();
#pragma unroll
    for (int kk = 0; kk < 2; ++kk) {
      bf16x8 af[4], bfr[4];
#pragma unroll
      for (int i = 0; i < 4; ++i)
        af[i] = *(const bf16x8*)(As + (wr * 64 + i * 16 + li) * 64 + kk * 32 + g * 8);
#pragma unroll
      for (int j = 0; j < 4; ++j)
        bfr[j] = *(const bf16x8*)(Bs + (wc * 64 + j * 16 + li) * 64 + kk * 32 + g * 8);
#pragma unroll
      for (int i = 0; i < 4; ++i)
#pragma unroll
        for (int j = 0; j < 4; ++j)
          acc[i][j] = MFMA_BF16(af[i], bfr[j], acc[i][j]);
    }
    __syncthreads();
  }

#pragma unroll
  for (int i = 0; i < 4; ++i) {
#pragma unroll
    for (int j = 0; j < 4; ++j) {
      int col = n0 + wc * 64 + j * 16 + li;
      int h = col / 192, r = col % 192;
#pragma unroll
      for (int rg = 0; rg < 4; ++rg) {
        int row = m0 + wr * 64 + i * 16 + g * 4 + rg;
        int b = row >> 10, l = row & 1023;
        bf16 v = (bf16)acc[i][j][rg];
        if (r < 64)
          Q[((size_t)((b * 16 + h) * 1024 + l)) * 64 + r] = v;
        else if (r < 128)
          Kc[((size_t)((b * 16 + h) * 1024 + l)) * 64 + (r - 64)] = v;
        else
          Vt[((size_t)((b * 16 + h) * 64 + (r - 128))) * 1024 + l] = v;
      }
    }
  }
}

// --------------------------------------------------------------------
// Kernel 2: flash attention per (b,h, q-tile of 64). 4 waves x 16 q-rows.
// K/V (bf16 ws) read straight from global (L2-resident, reused 16x).
// bias f32, mask int32 streamed from global. Online softmax with finite
// NEG (reproduces reference all-masked-row -> uniform behavior).
// Output Vals bf16 in [B, L, H*A] layout.
// --------------------------------------------------------------------
__global__ __launch_bounds__(256) void k_attn(const bf16* __restrict__ Q,
                                              const bf16* __restrict__ Kc,
                                              const bf16* __restrict__ Vt,
                                              const float* __restrict__ bias,
                                              const int* __restrict__ mask,
                                              bf16* __restrict__ Vals) {
  __shared__ __align__(16) bf16 Plds[4][16][72];  // per-wave, padded rows
  const int t = threadIdx.x, lane = t & 63, w = t >> 6;
  const int li = lane & 15, g = lane >> 4;
  const int bh = blockIdx.y;           // b*16+h
  const int b = bh >> 4, h = bh & 15;
  const int q0 = blockIdx.x * 64 + w * 16;  // wave's 16 q rows

  const bf16* Qbase = Q + ((size_t)bh << 10) * 64;
  const bf16* Kbase = Kc + ((size_t)bh << 10) * 64;
  const bf16* Vbase = Vt + ((size_t)bh << 6) * 1024;
  const size_t bm0 = ((size_t)bh << 20);

  bf16x8 qf[2];
#pragma unroll
  for (int c = 0; c < 2; ++c)
    qf[c] = *(const bf16x8*)(Qbase + (size_t)(q0 + li) * 64 + c * 32 + g * 8);

  f32x4 oacc[4] = {};
  float mrun[4] = {NEGF, NEGF, NEGF, NEGF};
  float lrun[4] = {0.f, 0.f, 0.f, 0.f};

  for (int kkt = 0; kkt < 1024; kkt += 64) {
    // ---- S = Q K^T (per wave: 16q x 64k as 4 fragments) ----
    f32x4 s[4];
#pragma unroll
    for (int kkf = 0; kkf < 4; ++kkf) {
      f32x4 ss = {0.f, 0.f, 0.f, 0.f};
#pragma unroll
      for (int c = 0; c < 2; ++c) {
        bf16x8 kf = *(const bf16x8*)(Kbase + (size_t)(kkt + kkf * 16 + li) * 64 + c * 32 + g * 8);
        ss = MFMA_BF16(qf[c], kf, ss);
      }
      s[kkf] = ss;
    }
    // ---- scale + bias + mask ----
    float tmax[4] = {NEGF, NEGF, NEGF, NEGF};
#pragma unroll
    for (int kkf = 0; kkf < 4; ++kkf) {
#pragma unroll
      for (int rg = 0; rg < 4; ++rg) {
        size_t idx = bm0 + (size_t)(q0 + g * 4 + rg) * 1024 + kkt + kkf * 16 + li;
        float sv = s[kkf][rg] * SCALE_ + bias[idx];
        sv = mask[idx] ? NEGF : sv;
        s[kkf][rg] = sv;
        tmax[rg] = fmaxf(tmax[rg], sv);
      }
    }
    // ---- row max across the 16-lane group ----
#pragma unroll
    for (int rg = 0; rg < 4; ++rg) {
      float v = tmax[rg];
#pragma unroll
      for (int d = 1; d < 16; d <<= 1) v = fmaxf(v, __shfl_xor(v, d));
      tmax[rg] = v;
    }
    float mnew[4], corr[4], psum[4];
#pragma unroll
    for (int rg = 0; rg < 4; ++rg) {
      mnew[rg] = fmaxf(mrun[rg], tmax[rg]);
      corr[rg] = __expf(mrun[rg] - mnew[rg]);  // NEG-NEG=0 -> 1; NEG-real -> 0
      psum[rg] = 0.f;
    }
    // ---- P = exp(s - m), stash to LDS for transpose ----
#pragma unroll
    for (int kkf = 0; kkf < 4; ++kkf) {
#pragma unroll
      for (int rg = 0; rg < 4; ++rg) {
        float p = __expf(s[kkf][rg] - mnew[rg]);
        psum[rg] += p;
        Plds[w][g * 4 + rg][kkf * 16 + li] = (bf16)p;
      }
    }
#pragma unroll
    for (int rg = 0; rg < 4; ++rg) {
      float v = psum[rg];
#pragma unroll
      for (int d = 1; d < 16; d <<= 1) v += __shfl_xor(v, d);
      lrun[rg] = lrun[rg] * corr[rg] + v;
      mrun[rg] = mnew[rg];
    }
#pragma unroll
    for (int af = 0; af < 4; ++af)
#pragma unroll
      for (int rg = 0; rg < 4; ++rg) oacc[af][rg] *= corr[rg];
    __syncthreads();
    // ---- O += P V  (P from LDS as A-operand, Vt as B-operand) ----
#pragma unroll
    for (int c = 0; c < 2; ++c) {
      bf16x8 pf = *(const bf16x8*)(&Plds[w][li][c * 32 + g * 8]);
#pragma unroll
      for (int af = 0; af < 4; ++af) {
        bf16x8 vf = *(const bf16x8*)(Vbase + (size_t)(af * 16 + li) * 1024 + kkt + c * 32 + g * 8);
        oacc[af] = MFMA_BF16(pf, vf, oacc[af]);
      }
    }
    __syncthreads();
  }

#pragma unroll
  for (int af = 0; af < 4; ++af) {
#pragma unroll
    for (int rg = 0; rg < 4; ++rg) {
      int q = q0 + g * 4 + rg;
      int col = h * 64 + af * 16 + li;
      Vals[(((size_t)(b * 1024 + q)) << 10) + col] = (bf16)(oacc[af][rg] / lrun[rg]);
    }
  }
}

// --------------------------------------------------------------------
// Kernel 3: output projection. out[8192,1024] = Vals @ Wout[1024,1024]^T
// A (Vals) is bf16 -> global_load_lds; B (Wout) is f32 -> reg-stage+cvt.
// Output f32.
// --------------------------------------------------------------------
__global__ __launch_bounds__(256) void k_out(const bf16* __restrict__ X,
                                             const float* __restrict__ W,
                                             float* __restrict__ Out) {
  constexpr int K = 1024;
  __shared__ __align__(16) bf16 As[128 * 64];
  __shared__ __align__(16) bf16 Bs[128 * 64];
  const int t = threadIdx.x;
  const int lane = t & 63, w = t >> 6;
  const int wr = w >> 1, wc = w & 1;
  const int li = lane & 15, g = lane >> 4;
  const int m0 = (blockIdx.x & 63) * 128;   // 64 m-tiles
  const int n0 = (blockIdx.x >> 6) * 128;   // 8 n-tiles

  f32x4 acc[4][4] = {};

  for (int kt = 0; kt < K; kt += 64) {
#pragma unroll
    for (int it = 0; it < 4; ++it) {
      int c = it * 256 + t;
      int row = c >> 3, col = (c & 7) << 3;
      gload_lds16(X + (size_t)(m0 + row) * K + kt + col, As + c * 8);
      *(bf16x8*)(Bs + c * 8) = cvt8(W + (size_t)(n0 + row) * K + kt + col);
    }
    __syncthreads();
#pragma unroll
    for (int kk = 0; kk < 2; ++kk) {
      bf16x8 af[4], bfr[4];
#pragma unroll
      for (int i = 0; i < 4; ++i)
        af[i] = *(const bf16x8*)(As + (wr * 64 + i * 16 + li) * 64 + kk * 32 + g * 8);
#pragma unroll
      for (int j = 0; j < 4; ++j)
        bfr[j] = *(const bf16x8*)(Bs + (wc * 64 + j * 16 + li) * 64 + kk * 32 + g * 8);
#pragma unroll
      for (int i = 0; i < 4; ++i)
#pragma unroll
        for (int j = 0; j < 4; ++j)
          acc[i][j] = MFMA_BF16(af[i], bfr[j], acc[i][j]);
    }
    __syncthreads();
  }

#pragma unroll
  for (int i = 0; i < 4; ++i) {
#pragma unroll
    for (int j = 0; j < 4; ++j) {
      int col = n0 + wc * 64 + j * 16 + li;
#pragma unroll
      for (int rg = 0; rg < 4; ++rg) {
        int row = m0 + wr * 64 + i * 16 + g * 4 + rg;
        Out[((size_t)row << 10) + col] = acc[i][j][rg];
      }
    }
  }
}

// --------------------------------------------------------------------
extern "C" void kernel_launch(void* const* d_in, const int* in_sizes, int n_in,
                              void* d_out, int out_size, void* d_ws, size_t ws_size,
                              hipStream_t stream) {
  const float* emb  = (const float*)d_in[0];
  const int*   mask = (const int*)d_in[1];
  const float* bias = (const float*)d_in[2];
  const float* Wqkv = (const float*)d_in[3];
  const float* Wout = (const float*)d_in[4];
  float* out = (float*)d_out;

  const size_t HEADS_ELEMS = (size_t)8 * 16 * 1024 * 64;  // 8.39M elems
  bf16* Q    = (bf16*)d_ws;
  bf16* Kc   = Q + HEADS_ELEMS;
  bf16* Vt   = Kc + HEADS_ELEMS;
  bf16* Vals = Vt + HEADS_ELEMS;   // total ~67 MiB of ws

  k_qkv<<<dim3(64 * 24), 256, 0, stream>>>(emb, Wqkv, Q, Kc, Vt);
  k_attn<<<dim3(16, 128), 256, 0, stream>>>(Q, Kc, Vt, bias, mask, Vals);
  k_out<<<dim3(64 * 8), 256, 0, stream>>>(Vals, Wout, out);
}